// Round 4
// baseline (114.944 us; speedup 1.0000x reference)
//
#include <hip/hip_runtime.h>
#include <hip/hip_bf16.h>
#include <stdint.h>

#define AS1 __attribute__((address_space(1)))
#define AS3 __attribute__((address_space(3)))

typedef __attribute__((ext_vector_type(8))) short bf16x8_t;
typedef __attribute__((ext_vector_type(4))) float f32x4_t;

#define DDIM 1024

// fp32 -> bf16 round-to-nearest-even (software path, used in transpose_w).
static __device__ inline ushort f32_to_bf16_rne(float f) {
  union { float f; uint32_t u; } v;
  v.f = f;
  v.u += 0x7FFFu + ((v.u >> 16) & 1u);
  return (ushort)(v.u >> 16);
}

// ---------------------------------------------------------------------------
// One-time transpose+convert: Wt[n][k] = bf16(W[k][n]), W fp32 1024x1024.
// ~6 MiB traffic -> ~2 us. X conversion is fused into the GEMM.
// ---------------------------------------------------------------------------
__global__ __launch_bounds__(256) void transpose_w(const float* __restrict__ W,
                                                   ushort* __restrict__ Wt) {
  __shared__ float tile[64][65];
  const int t  = threadIdx.x;
  const int bk = blockIdx.x;
  const int bn = blockIdx.y;
#pragma unroll
  for (int s = 0; s < 4; ++s) {
    const int slot = (s << 8) + t;
    const int r    = slot >> 4;
    const int c4   = (slot & 15) << 2;
    const float4 v = *(const float4*)(W + (size_t)(bk * 64 + r) * DDIM + bn * 64 + c4);
    tile[r][c4 + 0] = v.x; tile[r][c4 + 1] = v.y;
    tile[r][c4 + 2] = v.z; tile[r][c4 + 3] = v.w;
  }
  __syncthreads();
#pragma unroll
  for (int s = 0; s < 2; ++s) {
    const int slot = (s << 8) + t;
    const int n    = slot >> 3;
    const int k8   = (slot & 7) << 3;
    union { ushort h[8]; uint4 u; } tmp;
#pragma unroll
    for (int j = 0; j < 8; ++j) tmp.h[j] = f32_to_bf16_rne(tile[k8 + j][n]);
    *(uint4*)(Wt + (size_t)(bn * 64 + n) * DDIM + bk * 64 + k8) = tmp.u;
  }
}

// ---------------------------------------------------------------------------
// Main GEMM: C[fp32 8192x1024] = bf16(X) * Wt^T, A-conversion fused.
//
// ROUND-8: round-7's counters showed the fused-A gemm latency-bound
// (MfmaUtil 14.7 / VALU 10 / HBM 18 / Occ 15 -- all idle): writeA(i+1)
// consumed av[] only ~300 cyc after issue, but X loads take ~600-900 cyc
// (HBM/L3). Fix: A register pipeline at DISTANCE 2 -- two named buffers
// av0/av1 (static indexing, rule #20), loadA(i+2) issued at iter i, so
// each A-load gets ~2 compute phases of flight before its cvt+ds_write.
// Steady-state newest-in-flight at the pre-compute wait = 8 A(i+2) +
// 4 B(i+1) -> vmcnt(12) retires exactly B(i) AND A(i+1): writeA never
// stalls. B stays on global_load_lds (proven fastest staging path).
//
// Staging maps (rule #21 -- same involution on write & read):
//   B (gload_lds, LDS dest linear): source pre-swizzled, thread t covers
//     row sr=t>>3 of each 32-row band, chunk sc=(t&7)^(sr&7).
//   A (reg-staged): source LINEAR (coalesced), chunk gc=t&7; LDS write
//     slot gc^(sr&7). Read side (A and B): slot kc^(r&7).
//
// Barrier #1 (pre-compute):  vmcnt(12) + s_barrier -- tile i fully in LDS.
// Barrier #2 (post-compute): lgkmcnt(0) + s_barrier -- A(i+1) ds_writes
//   visible AND all waves' ds_reads of buf p complete (lgkmcnt counts
//   both), so iter i+1 may overwrite buf p via gload_lds.
// ---------------------------------------------------------------------------
__global__ __launch_bounds__(256, 2) void gemm_fa2(const float* __restrict__ X,
                                                   const ushort* __restrict__ Wt,
                                                   float* __restrict__ C) {
  __shared__ __align__(16) ushort As[2][128 * 64];  // 2 x 16 KB
  __shared__ __align__(16) ushort Bs[2][128 * 64];  // 2 x 16 KB

  const int t    = threadIdx.x;
  const int wave = t >> 6;
  const int lane = t & 63;
  const int m0 = blockIdx.x * 128;
  const int n0 = blockIdx.y * 128;

  const int sr = t >> 3;          // row 0..31 within each 32-row band
  const int gc = t & 7;           // A: linear global chunk (coalesced)
  const int sc = gc ^ (sr & 7);   // B: pre-swizzled global chunk
  const int slotA = sc;           // A LDS write slot = gc ^ (sr&7)

  const float*  aB = X  + (size_t)(m0 + sr) * DDIM + (gc << 3);
  const ushort* bB = Wt + (size_t)(n0 + sr) * DDIM + (sc << 3);

  AS3 char* lB = (AS3 char*)&Bs[0][0];
  const int woff = wave << 10;

  // Wave tile: 64x64, 4x4 frags of 16x16x32.
  const int wr = (wave >> 1) << 6;
  const int wc = (wave & 1) << 6;
  const int fr = lane & 15;
  const int fq = lane >> 4;

  f32x4_t acc[4][4] = {};

  float4 av0[8], av1[8];  // A fp32 pipeline, distance 2 (named: rule #20)

  auto loadA0 = [&](int kt) {
    const float* a = aB + kt;
#pragma unroll
    for (int j = 0; j < 4; ++j) {
      av0[2 * j + 0] = *(const float4*)(a + (size_t)(j << 5) * DDIM);
      av0[2 * j + 1] = *(const float4*)(a + (size_t)(j << 5) * DDIM + 4);
    }
  };
  auto loadA1 = [&](int kt) {
    const float* a = aB + kt;
#pragma unroll
    for (int j = 0; j < 4; ++j) {
      av1[2 * j + 0] = *(const float4*)(a + (size_t)(j << 5) * DDIM);
      av1[2 * j + 1] = *(const float4*)(a + (size_t)(j << 5) * DDIM + 4);
    }
  };

  auto issueB = [&](int kt, int p) {
    const ushort* b = bB + kt;
    AS3 char* dB = lB + (p << 14) + woff;
#pragma unroll
    for (int j = 0; j < 4; ++j) {
      __builtin_amdgcn_global_load_lds((const AS1 void*)(b + (size_t)(j << 5) * DDIM),
                                       (AS3 void*)(dB + (j << 12)), 16, 0, 0);
    }
  };

  auto writeA0 = [&](int pn) {
#pragma unroll
    for (int j = 0; j < 4; ++j) {
      const float4 u0 = av0[2 * j + 0];
      const float4 u1 = av0[2 * j + 1];
      uint4 w;
      asm("v_cvt_pk_bf16_f32 %0, %1, %2" : "=v"(w.x) : "v"(u0.x), "v"(u0.y));
      asm("v_cvt_pk_bf16_f32 %0, %1, %2" : "=v"(w.y) : "v"(u0.z), "v"(u0.w));
      asm("v_cvt_pk_bf16_f32 %0, %1, %2" : "=v"(w.z) : "v"(u1.x), "v"(u1.y));
      asm("v_cvt_pk_bf16_f32 %0, %1, %2" : "=v"(w.w) : "v"(u1.z), "v"(u1.w));
      const int r = sr + (j << 5);
      *(uint4*)&As[pn][(r << 6) + (slotA << 3)] = w;
    }
  };
  auto writeA1 = [&](int pn) {
#pragma unroll
    for (int j = 0; j < 4; ++j) {
      const float4 u0 = av1[2 * j + 0];
      const float4 u1 = av1[2 * j + 1];
      uint4 w;
      asm("v_cvt_pk_bf16_f32 %0, %1, %2" : "=v"(w.x) : "v"(u0.x), "v"(u0.y));
      asm("v_cvt_pk_bf16_f32 %0, %1, %2" : "=v"(w.y) : "v"(u0.z), "v"(u0.w));
      asm("v_cvt_pk_bf16_f32 %0, %1, %2" : "=v"(w.z) : "v"(u1.x), "v"(u1.y));
      asm("v_cvt_pk_bf16_f32 %0, %1, %2" : "=v"(w.w) : "v"(u1.z), "v"(u1.w));
      const int r = sr + (j << 5);
      *(uint4*)&As[pn][(r << 6) + (slotA << 3)] = w;
    }
  };

  auto compute = [&](int p) {
    const ushort* Ab = &As[p][0];
    const ushort* Bb = &Bs[p][0];
#pragma unroll
    for (int ks = 0; ks < 2; ++ks) {
      const int kc = (ks << 2) + fq;  // chunk 0..7
      bf16x8_t af[4], bfr[4];
#pragma unroll
      for (int mi = 0; mi < 4; ++mi) {
        const int r = wr + (mi << 4) + fr;
        af[mi] = *(const bf16x8_t*)&Ab[(r << 6) + ((kc ^ (r & 7)) << 3)];
      }
#pragma unroll
      for (int ni = 0; ni < 4; ++ni) {
        const int r = wc + (ni << 4) + fr;
        bfr[ni] = *(const bf16x8_t*)&Bb[(r << 6) + ((kc ^ (r & 7)) << 3)];
      }
#pragma unroll
      for (int mi = 0; mi < 4; ++mi)
#pragma unroll
        for (int ni = 0; ni < 4; ++ni)
          acc[mi][ni] = __builtin_amdgcn_mfma_f32_16x16x32_bf16(af[mi], bfr[ni], acc[mi][ni], 0, 0, 0);
    }
  };

  // ---- Prologue: tiles 0 (full stage) and 1 (A in regs). ----
  loadA0(0);        // 8 loads
  issueB(0, 0);     // 4
  loadA1(1 << 6);   // 8 (newest)
  writeA0(0);       // reg-dep waits av0 only; cvt + ds_write buf0
  // Retire B(0) (leave A(1)'s 8 in flight); A(0) ds_writes visible.
  asm volatile("s_waitcnt vmcnt(8) lgkmcnt(0)\n\ts_barrier" ::: "memory");

  // ---- Steady state: iters 0..13, 2-unrolled (static av parity). ----
  for (int ii = 0; ii < 7; ++ii) {
    const int i0 = ii << 1;
    // iter i0 (p=0): av1 holds tile i0+1
    loadA0((i0 + 2) << 6);
    issueB((i0 + 1) << 6, 1);
    asm volatile("s_waitcnt vmcnt(12)\n\ts_barrier" ::: "memory");  // B(i0), A(i0+1) retired
    compute(0);
    writeA1(1);
    asm volatile("s_waitcnt lgkmcnt(0)\n\ts_barrier" ::: "memory");
    // iter i0+1 (p=1): av0 holds tile i0+2
    loadA1((i0 + 3) << 6);
    issueB((i0 + 2) << 6, 0);
    asm volatile("s_waitcnt vmcnt(12)\n\ts_barrier" ::: "memory");
    compute(1);
    writeA0(0);
    asm volatile("s_waitcnt lgkmcnt(0)\n\ts_barrier" ::: "memory");
  }

  // ---- Tail: iters 14, 15. (av1 holds tile 15 from loadA1 at ii=6.) ----
  issueB(15 << 6, 1);
  // Outstanding: A(15)=8 older + B(15)=4 newest -> vmcnt(4) retires A(15), B(14).
  asm volatile("s_waitcnt vmcnt(4)\n\ts_barrier" ::: "memory");
  compute(0);       // tile 14
  writeA1(1);       // tile 15 -> buf1
  asm volatile("s_waitcnt lgkmcnt(0)\n\ts_barrier" ::: "memory");
  asm volatile("s_waitcnt vmcnt(0)\n\ts_barrier" ::: "memory");  // B(15) landed
  compute(1);       // tile 15

  // Epilogue. C/D layout: col = lane&15, row = (lane>>4)*4 + reg.
#pragma unroll
  for (int mi = 0; mi < 4; ++mi) {
#pragma unroll
    for (int r = 0; r < 4; ++r) {
      const int row = m0 + wr + (mi << 4) + (fq << 2) + r;
      float* crow = C + (size_t)row * DDIM + n0 + wc + fr;
#pragma unroll
      for (int ni = 0; ni < 4; ++ni)
        crow[ni << 4] = acc[mi][ni][r];
    }
  }
}

// ---------------------------------------------------------------------------
// softmax over the size-1 sequence axis == 1.0 exactly -> out = x @ kernel[2].
// ---------------------------------------------------------------------------
extern "C" void kernel_launch(void* const* d_in, const int* in_sizes, int n_in,
                              void* d_out, int out_size, void* d_ws, size_t ws_size,
                              hipStream_t stream) {
  const float* x    = (const float*)d_in[0];
  const float* kern = (const float*)d_in[1];
  const float* W = kern + (size_t)2 * DDIM * DDIM;  // kernel[2] — V projection
  ushort* Wt = (ushort*)d_ws;                       // needs only 2 MiB of ws
  const int M = in_sizes[0] / DDIM;  // 8192

  transpose_w<<<dim3(DDIM / 64, DDIM / 64), 256, 0, stream>>>(W, Wt);
  gemm_fa2<<<dim3(M / 128, DDIM / 128), 256, 0, stream>>>(x, Wt, (float*)d_out);
}